// Round 1
// baseline (632.626 us; speedup 1.0000x reference)
//
#include <hip/hip_runtime.h>

typedef float    f32x4 __attribute__((ext_vector_type(4)));
typedef _Float16 f16x8 __attribute__((ext_vector_type(8)));

#define T_TOK 4096
#define HD    1024
#define ID    4096
#define NE    8
#define TOTP  (2*T_TOK)
#define BM    128
#define BN    128
#define BK    32
#define MAXTILES 72

// ---- workspace layout (bytes). Total ~96.2 MB ----
#define WS_CNT   0                       // int[8]   per-expert pair count
#define WS_FILL  32                      // int[8]   scatter fill cursor
#define WS_OFF   64                      // int[9]   pair-segment offsets
#define WS_TOT   128                     // int      total M-tiles
#define WS_TEXP  192                     // int[MAXTILES] tile -> expert
#define WS_TM0   (192 + 4*MAXTILES)      // int[MAXTILES] tile -> m0 within segment
#define WS_TOPE  1024                    // int[TOTP]   top-2 expert ids (t*2+slot)
#define WS_TOPW  (WS_TOPE + 4*TOTP)      // float[TOTP] routing weights
#define WS_PAIR  (WS_TOPW + 4*TOTP)      // int[TOTP]   concatenated expert lists (t*2+slot)
#define WS_ACT   131072                  // f16[TOTP*ID]  silu(gate)*up, row = pair position
#define WS_YBUF  ((size_t)WS_ACT + 2ull*TOTP*ID) // float[TOTP*HD], row = t*2+slot

// round-to-nearest f32 -> f16 happens via plain cast (v_cvt_f16_f32)

__device__ __forceinline__ int lofs(int row, int g) {
  // [row][BK] f16 tile, 16B-granule XOR swizzle -> bank-floor reads AND writes
  return row * BK + ((g ^ ((row >> 1) & 3)) << 3);
}

// ---------------- routing ----------------
__global__ void k_router(const float* __restrict__ logits, char* __restrict__ ws) {
  int t = blockIdx.x * blockDim.x + threadIdx.x;
  if (t >= T_TOK) return;
  float v0 = -1e30f, v1 = -1e30f; int i0 = 0, i1 = 0;
  #pragma unroll
  for (int e = 0; e < NE; ++e) {
    float v = logits[t * NE + e];
    if (v > v0)      { v1 = v0; i1 = i0; v0 = v; i0 = e; }
    else if (v > v1) { v1 = v;  i1 = e; }
  }
  float w0 = 1.f / (1.f + __expf(v1 - v0));   // softmax over {v0,v1}
  ((int*)(ws + WS_TOPE))[2*t]   = i0;
  ((int*)(ws + WS_TOPE))[2*t+1] = i1;
  ((float*)(ws + WS_TOPW))[2*t]   = w0;
  ((float*)(ws + WS_TOPW))[2*t+1] = 1.f - w0;
  atomicAdd(&((int*)(ws + WS_CNT))[i0], 1);
  atomicAdd(&((int*)(ws + WS_CNT))[i1], 1);
}

__global__ void k_prefix(char* __restrict__ ws) {
  if (threadIdx.x != 0 || blockIdx.x != 0) return;
  const int* cnt = (const int*)(ws + WS_CNT);
  int* off  = (int*)(ws + WS_OFF);
  int* texp = (int*)(ws + WS_TEXP);
  int* tm0  = (int*)(ws + WS_TM0);
  int run = 0, tiles = 0;
  for (int e = 0; e < NE; ++e) {
    off[e] = run;
    int ne = cnt[e];
    for (int i = 0; i < ne; i += BM) { texp[tiles] = e; tm0[tiles] = i; ++tiles; }
    run += ne;
  }
  off[NE] = run;
  *(int*)(ws + WS_TOT) = tiles;
}

__global__ void k_scatter(char* __restrict__ ws) {
  int t = blockIdx.x * blockDim.x + threadIdx.x;
  if (t >= T_TOK) return;
  const int* tope = (const int*)(ws + WS_TOPE);
  const int* off  = (const int*)(ws + WS_OFF);
  int* fill = (int*)(ws + WS_FILL);
  int* pair = (int*)(ws + WS_PAIR);
  #pragma unroll
  for (int s = 0; s < 2; ++s) {
    int id = 2*t + s;
    int e = tope[id];
    int pos = off[e] + atomicAdd(&fill[e], 1);
    pair[pos] = id;   // list order nondeterministic, but ybuf row = id -> output deterministic
  }
}

// ---------------- GEMM1: act[p] = silu(hs@Wg) * (hs@Wu), f16 out ----------------
__global__ __launch_bounds__(512) void k_gemm1(
    const float* __restrict__ hs, const float* __restrict__ Wg,
    const float* __restrict__ Wu, char* __restrict__ ws) {
  const int s = blockIdx.y;
  if (s >= *(const int*)(ws + WS_TOT)) return;
  const int e    = ((const int*)(ws + WS_TEXP))[s];
  const int m0   = ((const int*)(ws + WS_TM0))[s];
  const int offE = ((const int*)(ws + WS_OFF))[e];
  const int nE   = ((const int*)(ws + WS_CNT))[e];
  const int* __restrict__ pair = (const int*)(ws + WS_PAIR);
  _Float16* __restrict__ act = (_Float16*)(ws + WS_ACT);
  const int n0 = blockIdx.x * BN;
  const int tid = threadIdx.x;

  __shared__ _Float16 sm[2 * 3 * BM * BK];   // {A, Bg^T, Bu^T} double-buffered, 48 KB

  // A staging task: (row am, k-granule ag) — gathered token rows, coalesced along k
  const int am = tid >> 2, ag = tid & 3;
  int tok;
  { int mm = m0 + am; tok = (mm < nE) ? (pair[offE + mm] >> 1) : 0; }
  const float* __restrict__ aSrc = hs + (size_t)tok * HD + ag * 8;

  // B staging task: (col bn, k-granule bgk) — per-thread column => b128 LDS writes
  const int bn = tid & 127, bgk = tid >> 7;
  const size_t wbase = (size_t)e * HD * ID + (size_t)(bgk * 8) * ID + (size_t)(n0 + bn);
  const float* __restrict__ gSrc = Wg + wbase;
  const float* __restrict__ uSrc = Wu + wbase;

  float aR[8], gR[8], uR[8];
  auto issue = [&](int k0) {
    const float* ap = aSrc + k0;
    *(f32x4*)&aR[0] = *(const f32x4*)ap;
    *(f32x4*)&aR[4] = *(const f32x4*)(ap + 4);
    const float* gp = gSrc + (size_t)k0 * ID;
    const float* up = uSrc + (size_t)k0 * ID;
    #pragma unroll
    for (int j = 0; j < 8; ++j) { gR[j] = gp[(size_t)j * ID]; uR[j] = up[(size_t)j * ID]; }
  };
  auto writeb = [&](int buf) {
    _Float16* b0 = sm + buf * (3 * BM * BK);
    f16x8 av, gv, uv;
    #pragma unroll
    for (int j = 0; j < 8; ++j) { av[j] = (_Float16)aR[j]; gv[j] = (_Float16)gR[j]; uv[j] = (_Float16)uR[j]; }
    *(f16x8*)&b0[lofs(am, ag)] = av;
    *(f16x8*)&b0[BM*BK   + lofs(bn, bgk)] = gv;
    *(f16x8*)&b0[2*BM*BK + lofs(bn, bgk)] = uv;
  };

  const int lane = tid & 63, wid = tid >> 6;
  const int wr = wid >> 2, wc = wid & 3;      // 8 waves: 2(m)x4(n), wave tile 64x32
  const int l15 = lane & 15, l4 = lane >> 4;

  f32x4 accg[4][2] = {}, accu[4][2] = {};
  auto compute = [&](int buf) {
    const _Float16* b0 = sm + buf * (3 * BM * BK);
    f16x8 afr[4], gfr[2], ufr[2];
    #pragma unroll
    for (int i = 0; i < 4; ++i)
      afr[i] = *(const f16x8*)&b0[lofs(64*wr + 16*i + l15, l4)];
    #pragma unroll
    for (int j = 0; j < 2; ++j) {
      gfr[j] = *(const f16x8*)&b0[BM*BK   + lofs(32*wc + 16*j + l15, l4)];
      ufr[j] = *(const f16x8*)&b0[2*BM*BK + lofs(32*wc + 16*j + l15, l4)];
    }
    #pragma unroll
    for (int i = 0; i < 4; ++i)
      #pragma unroll
      for (int j = 0; j < 2; ++j) {
        accg[i][j] = __builtin_amdgcn_mfma_f32_16x16x32_f16(afr[i], gfr[j], accg[i][j], 0, 0, 0);
        accu[i][j] = __builtin_amdgcn_mfma_f32_16x16x32_f16(afr[i], ufr[j], accu[i][j], 0, 0, 0);
      }
  };

  issue(0); writeb(0); __syncthreads();
  const int KT = HD / BK;
  for (int kt = 0; kt < KT; ++kt) {
    const int cur = kt & 1;
    if (kt + 1 < KT) issue((kt + 1) * BK);   // loads in flight during compute
    compute(cur);
    if (kt + 1 < KT) writeb(cur ^ 1);
    __syncthreads();
  }

  // epilogue: fused silu(gate)*up, masked rows, f16 store
  #pragma unroll
  for (int i = 0; i < 4; ++i) {
    #pragma unroll
    for (int r = 0; r < 4; ++r) {
      const int mm = m0 + 64*wr + 16*i + 4*l4 + r;   // C/D: col=lane&15, row=(lane>>4)*4+r
      if (mm < nE) {
        const size_t prow = (size_t)(offE + mm) * ID;
        #pragma unroll
        for (int j = 0; j < 2; ++j) {
          float g = accg[i][j][r], u = accu[i][j][r];
          float sv = g / (1.f + __expf(-g)) * u;
          act[prow + n0 + 32*wc + 16*j + l15] = (_Float16)sv;
        }
      }
    }
  }
}

// ---------------- GEMM2: ybuf[id] = act[p] @ Wd[e] ----------------
__global__ __launch_bounds__(512) void k_gemm2(const float* __restrict__ Wd,
                                               char* __restrict__ ws) {
  const int s = blockIdx.y;
  if (s >= *(const int*)(ws + WS_TOT)) return;
  const int e    = ((const int*)(ws + WS_TEXP))[s];
  const int m0   = ((const int*)(ws + WS_TM0))[s];
  const int offE = ((const int*)(ws + WS_OFF))[e];
  const int nE   = ((const int*)(ws + WS_CNT))[e];
  const int* __restrict__ pair = (const int*)(ws + WS_PAIR);
  const _Float16* __restrict__ act = (const _Float16*)(ws + WS_ACT);
  float* __restrict__ ybuf = (float*)(ws + WS_YBUF);
  const int n0 = blockIdx.x * BN;
  const int tid = threadIdx.x;

  __shared__ _Float16 sm[2 * 2 * BM * BK];   // {A, B^T} double-buffered, 32 KB

  const int am = tid >> 2, ag = tid & 3;
  int pA; { int mm = m0 + am; pA = (mm < nE) ? (offE + mm) : 0; }
  const _Float16* __restrict__ aSrc = act + (size_t)pA * ID + ag * 8;

  const int bn = tid & 127, bgk = tid >> 7;
  const float* __restrict__ bSrc = Wd + (size_t)e * ID * HD + (size_t)(bgk * 8) * HD + (size_t)(n0 + bn);

  f16x8 aV; float bR[8];
  auto issue = [&](int k0) {
    aV = *(const f16x8*)(aSrc + k0);
    const float* bp = bSrc + (size_t)k0 * HD;
    #pragma unroll
    for (int j = 0; j < 8; ++j) bR[j] = bp[(size_t)j * HD];
  };
  auto writeb = [&](int buf) {
    _Float16* b0 = sm + buf * (2 * BM * BK);
    f16x8 bv;
    #pragma unroll
    for (int j = 0; j < 8; ++j) bv[j] = (_Float16)bR[j];
    *(f16x8*)&b0[lofs(am, ag)] = aV;
    *(f16x8*)&b0[BM*BK + lofs(bn, bgk)] = bv;
  };

  const int lane = tid & 63, wid = tid >> 6;
  const int wr = wid >> 2, wc = wid & 3;
  const int l15 = lane & 15, l4 = lane >> 4;
  f32x4 acc[4][2] = {};
  auto compute = [&](int buf) {
    const _Float16* b0 = sm + buf * (2 * BM * BK);
    f16x8 afr[4], bfr[2];
    #pragma unroll
    for (int i = 0; i < 4; ++i)
      afr[i] = *(const f16x8*)&b0[lofs(64*wr + 16*i + l15, l4)];
    #pragma unroll
    for (int j = 0; j < 2; ++j)
      bfr[j] = *(const f16x8*)&b0[BM*BK + lofs(32*wc + 16*j + l15, l4)];
    #pragma unroll
    for (int i = 0; i < 4; ++i)
      #pragma unroll
      for (int j = 0; j < 2; ++j)
        acc[i][j] = __builtin_amdgcn_mfma_f32_16x16x32_f16(afr[i], bfr[j], acc[i][j], 0, 0, 0);
  };

  issue(0); writeb(0); __syncthreads();
  const int KT = ID / BK;
  for (int kt = 0; kt < KT; ++kt) {
    const int cur = kt & 1;
    if (kt + 1 < KT) issue((kt + 1) * BK);
    compute(cur);
    if (kt + 1 < KT) writeb(cur ^ 1);
    __syncthreads();
  }

  #pragma unroll
  for (int i = 0; i < 4; ++i) {
    #pragma unroll
    for (int r = 0; r < 4; ++r) {
      const int mm = m0 + 64*wr + 16*i + 4*l4 + r;
      if (mm < nE) {
        const int id = pair[offE + mm];
        #pragma unroll
        for (int j = 0; j < 2; ++j)
          ybuf[(size_t)id * HD + n0 + 32*wc + 16*j + l15] = acc[i][j][r];
      }
    }
  }
}

// ---------------- combine: out[t] = w0*y[t,0] + w1*y[t,1] ----------------
__global__ void k_combine(const char* __restrict__ ws, float* __restrict__ out) {
  const int idx = blockIdx.x * blockDim.x + threadIdx.x;  // over T*HD/4
  const int t = idx >> 8, c = idx & 255;                  // HD/4 = 256
  const float* topw = (const float*)(ws + WS_TOPW);
  const float* ybuf = (const float*)(ws + WS_YBUF);
  f32x4 y0 = ((const f32x4*)(ybuf + (size_t)(2*t)     * HD))[c];
  f32x4 y1 = ((const f32x4*)(ybuf + (size_t)(2*t + 1) * HD))[c];
  ((f32x4*)out)[idx] = topw[2*t] * y0 + topw[2*t+1] * y1;
}

extern "C" void kernel_launch(void* const* d_in, const int* in_sizes, int n_in,
                              void* d_out, int out_size, void* d_ws, size_t ws_size,
                              hipStream_t stream) {
  const float* hs     = (const float*)d_in[0];
  const float* logits = (const float*)d_in[1];
  const float* Wg     = (const float*)d_in[2];
  const float* Wu     = (const float*)d_in[3];
  const float* Wd     = (const float*)d_in[4];
  char* ws = (char*)d_ws;   // requires ~96.2 MB of workspace

  hipMemsetAsync(ws, 0, 64, stream);                       // cnt + fill
  k_router <<<dim3(T_TOK/256), dim3(256), 0, stream>>>(logits, ws);
  k_prefix <<<dim3(1),         dim3(64),  0, stream>>>(ws);
  k_scatter<<<dim3(T_TOK/256), dim3(256), 0, stream>>>(ws);
  k_gemm1  <<<dim3(ID/BN, MAXTILES), dim3(512), 0, stream>>>(hs, Wg, Wu, ws);
  k_gemm2  <<<dim3(HD/BN, MAXTILES), dim3(512), 0, stream>>>(Wd, ws);
  k_combine<<<dim3((T_TOK*HD/4)/256), dim3(256), 0, stream>>>(ws, (float*)d_out);
}

// Round 2
// 496.382 us; speedup vs baseline: 1.2745x; 1.2745x over previous
//
#include <hip/hip_runtime.h>

typedef float    f32x4 __attribute__((ext_vector_type(4)));
typedef _Float16 f16x8 __attribute__((ext_vector_type(8)));
typedef _Float16 f16x4 __attribute__((ext_vector_type(4)));

#define T_TOK 4096
#define HD    1024
#define ID    4096
#define NE    8
#define TOTP  (2*T_TOK)
#define BM    128
#define BN    128
#define MAXTILES 72

// ---- workspace layout (bytes). Total ~295 MB ----
#define WS_CNT   0
#define WS_FILL  64
#define WS_OFF   128
#define WS_TOT   192
#define WS_TEXP  256
#define WS_TM0   (256 + 4*MAXTILES)
#define WS_TOPE  1024
#define WS_TOPW  (WS_TOPE + 4*TOTP)
#define WS_PAIR  (WS_TOPW + 4*TOTP)
#define WS_ACT   ((size_t)1 << 20)                              // f16[TOTP*ID]   64 MB
constexpr size_t WS_YBUF = WS_ACT  + 2ull*TOTP*ID;              // f16[TOTP*HD]   16 MB
constexpr size_t WS_HS16 = WS_YBUF + 2ull*TOTP*HD;              // f16[T*HD]       8 MB
constexpr size_t WS_WG16 = WS_HS16 + 2ull*T_TOK*HD;             // f16[E][I][H]   67 MB
constexpr size_t WS_WU16 = WS_WG16 + 2ull*NE*HD*ID;             // f16[E][I][H]   67 MB
constexpr size_t WS_WD16 = WS_WU16 + 2ull*NE*HD*ID;             // f16[E][H][I]   67 MB

// async global->LDS, 16B per lane, wave-uniform LDS base
__device__ __forceinline__ void gll16(const void* g, void* l) {
  __builtin_amdgcn_global_load_lds(
      (const __attribute__((address_space(1))) unsigned int*)g,
      (__attribute__((address_space(3))) unsigned int*)l, 16, 0, 0);
}

// [row][32] f16 tile: 16B-granule XOR swizzle (2-way bank aliasing = free)
__device__ __forceinline__ int lofs(int row, int g) {
  return row * 32 + ((g ^ ((row >> 1) & 3)) << 3);
}
// [row][64] f16 tile (BK=64): 8 granules, swizzle with row&7
__device__ __forceinline__ int lofs64(int row, int g8) {
  return row * 64 + ((g8 ^ (row & 7)) << 3);
}

// ---------------- routing ----------------
__global__ void k_router(const float* __restrict__ logits, char* __restrict__ ws) {
  int t = blockIdx.x * blockDim.x + threadIdx.x;
  if (t >= T_TOK) return;
  float v0 = -1e30f, v1 = -1e30f; int i0 = 0, i1 = 0;
  #pragma unroll
  for (int e = 0; e < NE; ++e) {
    float v = logits[t * NE + e];
    if (v > v0)      { v1 = v0; i1 = i0; v0 = v; i0 = e; }
    else if (v > v1) { v1 = v;  i1 = e; }
  }
  float w0 = 1.f / (1.f + __expf(v1 - v0));
  ((int*)(ws + WS_TOPE))[2*t]   = i0;
  ((int*)(ws + WS_TOPE))[2*t+1] = i1;
  ((float*)(ws + WS_TOPW))[2*t]   = w0;
  ((float*)(ws + WS_TOPW))[2*t+1] = 1.f - w0;
  atomicAdd(&((int*)(ws + WS_CNT))[i0], 1);
  atomicAdd(&((int*)(ws + WS_CNT))[i1], 1);
}

__global__ void k_prefix(char* __restrict__ ws) {
  if (threadIdx.x != 0 || blockIdx.x != 0) return;
  const int* cnt = (const int*)(ws + WS_CNT);
  int* off  = (int*)(ws + WS_OFF);
  int* texp = (int*)(ws + WS_TEXP);
  int* tm0  = (int*)(ws + WS_TM0);
  int run = 0, tiles = 0;
  for (int e = 0; e < NE; ++e) {
    off[e] = run;
    int ne = cnt[e];
    for (int i = 0; i < ne; i += BM) { texp[tiles] = e; tm0[tiles] = i; ++tiles; }
    run += ne;
  }
  off[NE] = run;
  *(int*)(ws + WS_TOT) = tiles;
}

__global__ void k_scatter(char* __restrict__ ws) {
  int t = blockIdx.x * blockDim.x + threadIdx.x;
  if (t >= T_TOK) return;
  const int* tope = (const int*)(ws + WS_TOPE);
  const int* off  = (const int*)(ws + WS_OFF);
  int* fill = (int*)(ws + WS_FILL);
  int* pair = (int*)(ws + WS_PAIR);
  #pragma unroll
  for (int s = 0; s < 2; ++s) {
    int id = 2*t + s;
    int e = tope[id];
    int pos = off[e] + atomicAdd(&fill[e], 1);
    pair[pos] = id;   // order nondeterministic; ybuf row = id keeps output deterministic
  }
}

// ---------------- conversions ----------------
__global__ void k_hscvt(const float* __restrict__ src, _Float16* __restrict__ dst) {
  int i = blockIdx.x * blockDim.x + threadIdx.x;
  f32x4 v = ((const f32x4*)src)[i];
  f16x4 o;
  #pragma unroll
  for (int j = 0; j < 4; ++j) o[j] = (_Float16)v[j];
  ((f16x4*)dst)[i] = o;
}

// f32 [e][K][N] -> f16 [e][N][K], 64x64 tiles via LDS
__global__ __launch_bounds__(256) void k_wtrans(const float* __restrict__ src,
                                                _Float16* __restrict__ dst,
                                                int K, int N) {
  const int e = blockIdx.z;
  const int n0 = blockIdx.x * 64, k0 = blockIdx.y * 64;
  const float* s = src + (size_t)e * K * N;
  _Float16* d = dst + (size_t)e * (size_t)K * N;
  __shared__ _Float16 t[64][68];
  const int tx = threadIdx.x & 15, ty = threadIdx.x >> 4;
  #pragma unroll
  for (int it = 0; it < 4; ++it) {
    int k = k0 + it*16 + ty;
    f32x4 v = *(const f32x4*)&s[(size_t)k * N + n0 + tx*4];
    #pragma unroll
    for (int j = 0; j < 4; ++j) t[tx*4 + j][it*16 + ty] = (_Float16)v[j];
  }
  __syncthreads();
  #pragma unroll
  for (int it = 0; it < 4; ++it) {
    int n = it*16 + ty;
    *(f16x4*)&d[(size_t)(n0 + n) * K + k0 + tx*4] = *(const f16x4*)&t[n][tx*4];
  }
}

// ---------------- GEMM1: act[p] = silu(hs@Wg) * (hs@Wu), f16 ----------------
__global__ __launch_bounds__(512) void k_gemm1(
    const _Float16* __restrict__ hs16, const _Float16* __restrict__ WgT,
    const _Float16* __restrict__ WuT, char* __restrict__ ws) {
  const int s = blockIdx.y;
  if (s >= *(const int*)(ws + WS_TOT)) return;
  const int e    = ((const int*)(ws + WS_TEXP))[s];
  const int m0   = ((const int*)(ws + WS_TM0))[s];
  const int offE = ((const int*)(ws + WS_OFF))[e];
  const int nE   = ((const int*)(ws + WS_CNT))[e];
  _Float16* __restrict__ act = (_Float16*)(ws + WS_ACT);
  const int n0 = blockIdx.x * BN;
  const int tid = threadIdx.x, lane = tid & 63, wid = tid >> 6;

  __shared__ __align__(16) _Float16 sm[2 * 3 * BM * 32];   // 48 KB

  // staging: wave w covers rows 16w..16w+15 of each tile; lane -> (row, granule)
  // LDS dest is linear (gll requirement); source granule is inverse-swizzled (rule 21)
  const int rL = lane >> 2;
  const int q  = (((lane & 3) ^ ((lane >> 3) & 3)) << 3);
  int tok;
  { int mm = m0 + 16*wid + rL;
    tok = (mm < nE) ? (((const int*)(ws + WS_PAIR))[offE + mm] >> 1) : 0; }
  const _Float16* aS = hs16 + (size_t)tok * HD + q;
  const int colB = n0 + 16*wid + rL;
  const _Float16* gS = WgT + ((size_t)e * ID + colB) * HD + q;
  const _Float16* uS = WuT + ((size_t)e * ID + colB) * HD + q;

  auto stage = [&](int buf, int kt) {
    _Float16* b = sm + buf * (3*BM*32) + wid * 512;
    const int ko = kt * 32;
    gll16(aS + ko, b);
    gll16(gS + ko, b + BM*32);
    gll16(uS + ko, b + 2*BM*32);
  };

  const int wr = wid >> 2, wc = wid & 3;     // 8 waves: 2(m) x 4(n), wave tile 64x32
  const int l15 = lane & 15, l4 = lane >> 4;
  f32x4 accg[4][2] = {}, accu[4][2] = {};

  auto compute = [&](int buf) {
    const _Float16* b0 = sm + buf * (3*BM*32);
    f16x8 afr[4], gfr[2], ufr[2];
    #pragma unroll
    for (int i = 0; i < 4; ++i)
      afr[i] = *(const f16x8*)&b0[lofs(64*wr + 16*i + l15, l4)];
    #pragma unroll
    for (int j = 0; j < 2; ++j) {
      gfr[j] = *(const f16x8*)&b0[BM*32   + lofs(32*wc + 16*j + l15, l4)];
      ufr[j] = *(const f16x8*)&b0[2*BM*32 + lofs(32*wc + 16*j + l15, l4)];
    }
    #pragma unroll
    for (int i = 0; i < 4; ++i)
      #pragma unroll
      for (int j = 0; j < 2; ++j) {
        accg[i][j] = __builtin_amdgcn_mfma_f32_16x16x32_f16(afr[i], gfr[j], accg[i][j], 0, 0, 0);
        accu[i][j] = __builtin_amdgcn_mfma_f32_16x16x32_f16(afr[i], ufr[j], accu[i][j], 0, 0, 0);
      }
  };

  stage(0, 0);
  asm volatile("s_waitcnt vmcnt(0)" ::: "memory");
  __syncthreads();
  const int KT = HD / 32;
  for (int kt = 0; kt < KT; ++kt) {
    const int cur = kt & 1;
    if (kt + 1 < KT) stage(cur ^ 1, kt + 1);
    compute(cur);
    asm volatile("s_waitcnt vmcnt(0)" ::: "memory");
    __syncthreads();
  }

  #pragma unroll
  for (int i = 0; i < 4; ++i)
    #pragma unroll
    for (int r = 0; r < 4; ++r) {
      const int mm = m0 + 64*wr + 16*i + 4*l4 + r;   // C/D: col=lane&15, row=(lane>>4)*4+r
      if (mm < nE) {
        const size_t prow = (size_t)(offE + mm) * ID;
        #pragma unroll
        for (int j = 0; j < 2; ++j) {
          float g = accg[i][j][r], u = accu[i][j][r];
          float sv = g / (1.f + __expf(-g)) * u;
          act[prow + n0 + 32*wc + 16*j + l15] = (_Float16)sv;
        }
      }
    }
}

// ---------------- GEMM2: ybuf[id] = act[p] @ WdT[e], BK=64 ----------------
__global__ __launch_bounds__(512) void k_gemm2(const _Float16* __restrict__ WdT,
                                               char* __restrict__ ws) {
  const int s = blockIdx.y;
  if (s >= *(const int*)(ws + WS_TOT)) return;
  const int e    = ((const int*)(ws + WS_TEXP))[s];
  const int m0   = ((const int*)(ws + WS_TM0))[s];
  const int offE = ((const int*)(ws + WS_OFF))[e];
  const int nE   = ((const int*)(ws + WS_CNT))[e];
  const int* __restrict__ pair = (const int*)(ws + WS_PAIR);
  const _Float16* __restrict__ act = (const _Float16*)(ws + WS_ACT);
  _Float16* __restrict__ ybuf = (_Float16*)(ws + WS_YBUF);
  const int n0 = blockIdx.x * BN;
  const int tid = threadIdx.x, lane = tid & 63, wid = tid >> 6;

  __shared__ __align__(16) _Float16 sm[2 * 2 * BM * 64];   // 64 KB

  // staging: wave w covers rows 16w..16w+15, two 8-row 1KB chunks per tile
  const int rL8 = lane >> 3;                     // 0..7
  const int q8  = (((lane & 7) ^ rL8) << 3);     // inverse-swizzled source granule
  const int mmA0 = m0 + 16*wid + rL8, mmA1 = mmA0 + 8;
  const _Float16* aS0 = act + (size_t)(offE + (mmA0 < nE ? mmA0 : 0)) * ID + q8;
  const _Float16* aS1 = act + (size_t)(offE + (mmA1 < nE ? mmA1 : 0)) * ID + q8;
  const int cB = n0 + 16*wid + rL8;
  const _Float16* bS0 = WdT + ((size_t)e * HD + cB) * ID + q8;
  const _Float16* bS1 = bS0 + 8ull * ID;

  auto stage = [&](int buf, int kt) {
    _Float16* b = sm + buf * (2*BM*64) + wid * 1024;
    const int ko = kt * 64;
    gll16(aS0 + ko, b);
    gll16(aS1 + ko, b + 512);
    gll16(bS0 + ko, b + BM*64);
    gll16(bS1 + ko, b + BM*64 + 512);
  };

  const int wr = wid >> 2, wc = wid & 3;
  const int l15 = lane & 15, l4 = lane >> 4;
  f32x4 acc[4][2] = {};

  auto compute = [&](int buf) {
    const _Float16* b0 = sm + buf * (2*BM*64);
    #pragma unroll
    for (int ks = 0; ks < 2; ++ks) {
      f16x8 afr[4], bfr[2];
      #pragma unroll
      for (int i = 0; i < 4; ++i)
        afr[i] = *(const f16x8*)&b0[lofs64(64*wr + 16*i + l15, ks*4 + l4)];
      #pragma unroll
      for (int j = 0; j < 2; ++j)
        bfr[j] = *(const f16x8*)&b0[BM*64 + lofs64(32*wc + 16*j + l15, ks*4 + l4)];
      #pragma unroll
      for (int i = 0; i < 4; ++i)
        #pragma unroll
        for (int j = 0; j < 2; ++j)
          acc[i][j] = __builtin_amdgcn_mfma_f32_16x16x32_f16(afr[i], bfr[j], acc[i][j], 0, 0, 0);
    }
  };

  stage(0, 0);
  asm volatile("s_waitcnt vmcnt(0)" ::: "memory");
  __syncthreads();
  const int KT = ID / 64;
  for (int kt = 0; kt < KT; ++kt) {
    const int cur = kt & 1;
    if (kt + 1 < KT) stage(cur ^ 1, kt + 1);
    compute(cur);
    asm volatile("s_waitcnt vmcnt(0)" ::: "memory");
    __syncthreads();
  }

  #pragma unroll
  for (int i = 0; i < 4; ++i)
    #pragma unroll
    for (int r = 0; r < 4; ++r) {
      const int mm = m0 + 64*wr + 16*i + 4*l4 + r;
      if (mm < nE) {
        const int id = pair[offE + mm];
        #pragma unroll
        for (int j = 0; j < 2; ++j)
          ybuf[(size_t)id * HD + n0 + 32*wc + 16*j + l15] = (_Float16)acc[i][j][r];
      }
    }
}

// ---------------- combine ----------------
__global__ void k_combine(const char* __restrict__ ws, float* __restrict__ out) {
  const int idx = blockIdx.x * blockDim.x + threadIdx.x;   // over T*HD/8
  const int t = idx >> 7, c = idx & 127;
  const float* topw = (const float*)(ws + WS_TOPW);
  const _Float16* yb = (const _Float16*)(ws + WS_YBUF);
  f16x8 y0 = ((const f16x8*)(yb + (size_t)(2*t)     * HD))[c];
  f16x8 y1 = ((const f16x8*)(yb + (size_t)(2*t + 1) * HD))[c];
  const float w0 = topw[2*t], w1 = topw[2*t+1];
  f32x4 o0, o1;
  #pragma unroll
  for (int j = 0; j < 4; ++j) {
    o0[j] = w0 * (float)y0[j]     + w1 * (float)y1[j];
    o1[j] = w0 * (float)y0[4 + j] + w1 * (float)y1[4 + j];
  }
  ((f32x4*)out)[2*idx]     = o0;
  ((f32x4*)out)[2*idx + 1] = o1;
}

extern "C" void kernel_launch(void* const* d_in, const int* in_sizes, int n_in,
                              void* d_out, int out_size, void* d_ws, size_t ws_size,
                              hipStream_t stream) {
  const float* hs     = (const float*)d_in[0];
  const float* logits = (const float*)d_in[1];
  const float* Wg     = (const float*)d_in[2];
  const float* Wu     = (const float*)d_in[3];
  const float* Wd     = (const float*)d_in[4];
  char* ws = (char*)d_ws;   // requires ~295 MB of workspace

  _Float16* hs16 = (_Float16*)(ws + WS_HS16);
  _Float16* wg16 = (_Float16*)(ws + WS_WG16);
  _Float16* wu16 = (_Float16*)(ws + WS_WU16);
  _Float16* wd16 = (_Float16*)(ws + WS_WD16);

  hipMemsetAsync(ws, 0, 256, stream);
  k_router <<<dim3(T_TOK/256), dim3(256), 0, stream>>>(logits, ws);
  k_prefix <<<dim3(1),         dim3(64),  0, stream>>>(ws);
  k_scatter<<<dim3(T_TOK/256), dim3(256), 0, stream>>>(ws);
  k_hscvt  <<<dim3(T_TOK*HD/4/256), dim3(256), 0, stream>>>(hs, hs16);
  k_wtrans <<<dim3(ID/64, HD/64, NE), dim3(256), 0, stream>>>(Wg, wg16, HD, ID);
  k_wtrans <<<dim3(ID/64, HD/64, NE), dim3(256), 0, stream>>>(Wu, wu16, HD, ID);
  k_wtrans <<<dim3(HD/64, ID/64, NE), dim3(256), 0, stream>>>(Wd, wd16, ID, HD);
  k_gemm1  <<<dim3(ID/BN, MAXTILES), dim3(512), 0, stream>>>(hs16, wg16, wu16, ws);
  k_gemm2  <<<dim3(HD/BN, MAXTILES), dim3(512), 0, stream>>>(wd16, ws);
  k_combine<<<dim3(T_TOK*HD/8/256), dim3(256), 0, stream>>>(ws, (float*)d_out);
}

// Round 3
// 490.253 us; speedup vs baseline: 1.2904x; 1.0125x over previous
//
#include <hip/hip_runtime.h>

typedef float    f32x4 __attribute__((ext_vector_type(4)));
typedef _Float16 f16x8 __attribute__((ext_vector_type(8)));
typedef _Float16 f16x4 __attribute__((ext_vector_type(4)));

#define T_TOK 4096
#define HD    1024
#define ID    4096
#define NE    8
#define TOTP  (2*T_TOK)
#define BM    128
#define BN    128
#define MAXTILES 72

// ---- workspace layout (bytes). Total ~295 MB ----
#define WS_CNT   0
#define WS_FILL  64
#define WS_OFF   128
#define WS_TOT   192
#define WS_TEXP  256
#define WS_TM0   (256 + 4*MAXTILES)
#define WS_TOPE  1024
#define WS_TOPW  (WS_TOPE + 4*TOTP)
#define WS_PAIR  (WS_TOPW + 4*TOTP)
#define WS_ACT   ((size_t)1 << 20)                              // f16[TOTP*ID]   64 MB
constexpr size_t WS_YBUF = WS_ACT  + 2ull*TOTP*ID;              // f16[TOTP*HD]   16 MB
constexpr size_t WS_HS16 = WS_YBUF + 2ull*TOTP*HD;              // f16[T*HD]       8 MB
constexpr size_t WS_WG16 = WS_HS16 + 2ull*T_TOK*HD;             // f16[E][I][H]   67 MB
constexpr size_t WS_WU16 = WS_WG16 + 2ull*NE*HD*ID;             // f16[E][I][H]   67 MB
constexpr size_t WS_WD16 = WS_WU16 + 2ull*NE*HD*ID;             // f16[E][H][I]   67 MB

// async global->LDS, 16B per lane, wave-uniform LDS base
__device__ __forceinline__ void gll16(const void* g, void* l) {
  __builtin_amdgcn_global_load_lds(
      (const __attribute__((address_space(1))) unsigned int*)g,
      (__attribute__((address_space(3))) unsigned int*)l, 16, 0, 0);
}

#define WAITV(N) do { \
    asm volatile("s_waitcnt vmcnt(" #N ")" ::: "memory"); \
    __builtin_amdgcn_sched_barrier(0); \
  } while (0)

// [row][32] f16 tile: 16B-granule XOR swizzle (2-way bank aliasing = free)
__device__ __forceinline__ int lofs(int row, int g) {
  return row * 32 + ((g ^ ((row >> 1) & 3)) << 3);
}

// ---------------- routing ----------------
__global__ void k_router(const float* __restrict__ logits, char* __restrict__ ws) {
  int t = blockIdx.x * blockDim.x + threadIdx.x;
  if (t >= T_TOK) return;
  float v0 = -1e30f, v1 = -1e30f; int i0 = 0, i1 = 0;
  #pragma unroll
  for (int e = 0; e < NE; ++e) {
    float v = logits[t * NE + e];
    if (v > v0)      { v1 = v0; i1 = i0; v0 = v; i0 = e; }
    else if (v > v1) { v1 = v;  i1 = e; }
  }
  float w0 = 1.f / (1.f + __expf(v1 - v0));
  ((int*)(ws + WS_TOPE))[2*t]   = i0;
  ((int*)(ws + WS_TOPE))[2*t+1] = i1;
  ((float*)(ws + WS_TOPW))[2*t]   = w0;
  ((float*)(ws + WS_TOPW))[2*t+1] = 1.f - w0;
  atomicAdd(&((int*)(ws + WS_CNT))[i0], 1);
  atomicAdd(&((int*)(ws + WS_CNT))[i1], 1);
}

__global__ void k_prefix(char* __restrict__ ws) {
  if (threadIdx.x != 0 || blockIdx.x != 0) return;
  const int* cnt = (const int*)(ws + WS_CNT);
  int* off  = (int*)(ws + WS_OFF);
  int* texp = (int*)(ws + WS_TEXP);
  int* tm0  = (int*)(ws + WS_TM0);
  int run = 0, tiles = 0;
  for (int e = 0; e < NE; ++e) {
    off[e] = run;
    int ne = cnt[e];
    for (int i = 0; i < ne; i += BM) { texp[tiles] = e; tm0[tiles] = i; ++tiles; }
    run += ne;
  }
  off[NE] = run;
  *(int*)(ws + WS_TOT) = tiles;
}

__global__ void k_scatter(char* __restrict__ ws) {
  int t = blockIdx.x * blockDim.x + threadIdx.x;
  if (t >= T_TOK) return;
  const int* tope = (const int*)(ws + WS_TOPE);
  const int* off  = (const int*)(ws + WS_OFF);
  int* fill = (int*)(ws + WS_FILL);
  int* pair = (int*)(ws + WS_PAIR);
  #pragma unroll
  for (int s = 0; s < 2; ++s) {
    int id = 2*t + s;
    int e = tope[id];
    int pos = off[e] + atomicAdd(&fill[e], 1);
    pair[pos] = id;   // order nondeterministic; ybuf row = id keeps output deterministic
  }
}

// ---------------- conversions ----------------
__global__ void k_hscvt(const float* __restrict__ src, _Float16* __restrict__ dst) {
  int i = blockIdx.x * blockDim.x + threadIdx.x;
  f32x4 v = ((const f32x4*)src)[i];
  f16x4 o;
  #pragma unroll
  for (int j = 0; j < 4; ++j) o[j] = (_Float16)v[j];
  ((f16x4*)dst)[i] = o;
}

// f32 [e][K][N] -> f16 [e][N][K], 64x64 tiles via LDS
__global__ __launch_bounds__(256) void k_wtrans(const float* __restrict__ src,
                                                _Float16* __restrict__ dst,
                                                int K, int N) {
  const int e = blockIdx.z;
  const int n0 = blockIdx.x * 64, k0 = blockIdx.y * 64;
  const float* s = src + (size_t)e * K * N;
  _Float16* d = dst + (size_t)e * (size_t)K * N;
  __shared__ _Float16 t[64][68];
  const int tx = threadIdx.x & 15, ty = threadIdx.x >> 4;
  #pragma unroll
  for (int it = 0; it < 4; ++it) {
    int k = k0 + it*16 + ty;
    f32x4 v = *(const f32x4*)&s[(size_t)k * N + n0 + tx*4];
    #pragma unroll
    for (int j = 0; j < 4; ++j) t[tx*4 + j][it*16 + ty] = (_Float16)v[j];
  }
  __syncthreads();
  #pragma unroll
  for (int it = 0; it < 4; ++it) {
    int n = it*16 + ty;
    *(f16x4*)&d[(size_t)(n0 + n) * K + k0 + tx*4] = *(const f16x4*)&t[n][tx*4];
  }
}

// ---------------- GEMM1: act[p] = silu(hs@Wg) * (hs@Wu), f16 ----------------
// depth-2 counted-vmcnt pipeline, 3 LDS buffers (72 KB)
__global__ __launch_bounds__(512) void k_gemm1(
    const _Float16* __restrict__ hs16, const _Float16* __restrict__ WgT,
    const _Float16* __restrict__ WuT, char* __restrict__ ws) {
  const int s = blockIdx.y;
  if (s >= *(const int*)(ws + WS_TOT)) return;
  const int e    = ((const int*)(ws + WS_TEXP))[s];
  const int m0   = ((const int*)(ws + WS_TM0))[s];
  const int offE = ((const int*)(ws + WS_OFF))[e];
  const int nE   = ((const int*)(ws + WS_CNT))[e];
  _Float16* __restrict__ act = (_Float16*)(ws + WS_ACT);
  const int n0 = blockIdx.x * BN;
  const int tid = threadIdx.x, lane = tid & 63, wid = tid >> 6;

  __shared__ __align__(16) _Float16 sm[3 * 3 * BM * 32];   // 72 KB

  // staging: wave w covers rows 16w..16w+15; LDS dest linear, global src
  // granule inverse-swizzled (rule 21)
  const int rL = lane >> 2;
  const int q  = (((lane & 3) ^ ((lane >> 3) & 3)) << 3);
  int tok;
  { int mm = m0 + 16*wid + rL;
    tok = (mm < nE) ? (((const int*)(ws + WS_PAIR))[offE + mm] >> 1) : 0; }
  const _Float16* aS = hs16 + (size_t)tok * HD + q;
  const int colB = n0 + 16*wid + rL;
  const _Float16* gS = WgT + ((size_t)e * ID + colB) * HD + q;
  const _Float16* uS = WuT + ((size_t)e * ID + colB) * HD + q;

  auto stage = [&](int buf, int kt) {   // 3 gll16 per wave per tile
    _Float16* b = sm + buf * (3*BM*32) + wid * 512;
    const int ko = kt * 32;
    gll16(aS + ko, b);
    gll16(gS + ko, b + BM*32);
    gll16(uS + ko, b + 2*BM*32);
  };

  const int wr = wid >> 2, wc = wid & 3;     // 8 waves: 2(m) x 4(n), wave tile 64x32
  const int l15 = lane & 15, l4 = lane >> 4;
  f32x4 accg[4][2] = {}, accu[4][2] = {};

  auto compute = [&](int buf) {
    const _Float16* b0 = sm + buf * (3*BM*32);
    f16x8 afr[4], gfr[2], ufr[2];
    #pragma unroll
    for (int i = 0; i < 4; ++i)
      afr[i] = *(const f16x8*)&b0[lofs(64*wr + 16*i + l15, l4)];
    #pragma unroll
    for (int j = 0; j < 2; ++j) {
      gfr[j] = *(const f16x8*)&b0[BM*32   + lofs(32*wc + 16*j + l15, l4)];
      ufr[j] = *(const f16x8*)&b0[2*BM*32 + lofs(32*wc + 16*j + l15, l4)];
    }
    __builtin_amdgcn_s_setprio(1);
    #pragma unroll
    for (int i = 0; i < 4; ++i)
      #pragma unroll
      for (int j = 0; j < 2; ++j) {
        accg[i][j] = __builtin_amdgcn_mfma_f32_16x16x32_f16(afr[i], gfr[j], accg[i][j], 0, 0, 0);
        accu[i][j] = __builtin_amdgcn_mfma_f32_16x16x32_f16(afr[i], ufr[j], accu[i][j], 0, 0, 0);
      }
    __builtin_amdgcn_s_setprio(0);
  };

  const int KT = HD / 32;                    // 32
  stage(0, 0); stage(1, 1);
  for (int t = 0; t < KT - 2; ++t) {
    stage((t + 2) % 3, t + 2);               // overwrites buf read at iter t-1
    WAITV(6);                                // tile t landed; t+1,t+2 in flight
    __builtin_amdgcn_s_barrier();
    compute(t % 3);
    __builtin_amdgcn_s_barrier();            // readers done before restage
  }
  WAITV(3);
  __builtin_amdgcn_s_barrier();
  compute((KT - 2) % 3);
  __builtin_amdgcn_s_barrier();
  WAITV(0);
  __builtin_amdgcn_s_barrier();
  compute((KT - 1) % 3);

  #pragma unroll
  for (int i = 0; i < 4; ++i)
    #pragma unroll
    for (int r = 0; r < 4; ++r) {
      const int mm = m0 + 64*wr + 16*i + 4*l4 + r;   // C/D: col=lane&15, row=(lane>>4)*4+r
      if (mm < nE) {
        const size_t prow = (size_t)(offE + mm) * ID;
        #pragma unroll
        for (int j = 0; j < 2; ++j) {
          float g = accg[i][j][r], u = accu[i][j][r];
          float sv = g / (1.f + __expf(-g)) * u;
          act[prow + n0 + 32*wc + 16*j + l15] = (_Float16)sv;
        }
      }
    }
}

// ---------------- GEMM2: ybuf[id] = act[p] @ WdT[e] ----------------
// depth-2 counted-vmcnt pipeline, BK=32, 3 LDS buffers (48 KB)
__global__ __launch_bounds__(512) void k_gemm2(const _Float16* __restrict__ WdT,
                                               char* __restrict__ ws) {
  const int s = blockIdx.y;
  if (s >= *(const int*)(ws + WS_TOT)) return;
  const int e    = ((const int*)(ws + WS_TEXP))[s];
  const int m0   = ((const int*)(ws + WS_TM0))[s];
  const int offE = ((const int*)(ws + WS_OFF))[e];
  const int nE   = ((const int*)(ws + WS_CNT))[e];
  const int* __restrict__ pair = (const int*)(ws + WS_PAIR);
  const _Float16* __restrict__ act = (const _Float16*)(ws + WS_ACT);
  _Float16* __restrict__ ybuf = (_Float16*)(ws + WS_YBUF);
  const int n0 = blockIdx.x * BN;
  const int tid = threadIdx.x, lane = tid & 63, wid = tid >> 6;

  __shared__ __align__(16) _Float16 sm[3 * 2 * BM * 32];   // 48 KB

  const int rL = lane >> 2;
  const int q  = (((lane & 3) ^ ((lane >> 3) & 3)) << 3);
  int pA; { int mm = m0 + 16*wid + rL; pA = (mm < nE) ? (offE + mm) : 0; }
  const _Float16* aS = act + (size_t)pA * ID + q;
  const int cB = n0 + 16*wid + rL;
  const _Float16* bS = WdT + ((size_t)e * HD + cB) * ID + q;

  auto stage = [&](int buf, int kt) {   // 2 gll16 per wave per tile
    _Float16* b = sm + buf * (2*BM*32) + wid * 512;
    const int ko = kt * 32;
    gll16(aS + ko, b);
    gll16(bS + ko, b + BM*32);
  };

  const int wr = wid >> 2, wc = wid & 3;
  const int l15 = lane & 15, l4 = lane >> 4;
  f32x4 acc[4][2] = {};

  auto compute = [&](int buf) {
    const _Float16* b0 = sm + buf * (2*BM*32);
    f16x8 afr[4], bfr[2];
    #pragma unroll
    for (int i = 0; i < 4; ++i)
      afr[i] = *(const f16x8*)&b0[lofs(64*wr + 16*i + l15, l4)];
    #pragma unroll
    for (int j = 0; j < 2; ++j)
      bfr[j] = *(const f16x8*)&b0[BM*32 + lofs(32*wc + 16*j + l15, l4)];
    __builtin_amdgcn_s_setprio(1);
    #pragma unroll
    for (int i = 0; i < 4; ++i)
      #pragma unroll
      for (int j = 0; j < 2; ++j)
        acc[i][j] = __builtin_amdgcn_mfma_f32_16x16x32_f16(afr[i], bfr[j], acc[i][j], 0, 0, 0);
    __builtin_amdgcn_s_setprio(0);
  };

  const int KT = ID / 32;                    // 128
  stage(0, 0); stage(1, 1);
  for (int t = 0; t < KT - 2; ++t) {
    stage((t + 2) % 3, t + 2);
    WAITV(4);
    __builtin_amdgcn_s_barrier();
    compute(t % 3);
    __builtin_amdgcn_s_barrier();
  }
  WAITV(2);
  __builtin_amdgcn_s_barrier();
  compute((KT - 2) % 3);
  __builtin_amdgcn_s_barrier();
  WAITV(0);
  __builtin_amdgcn_s_barrier();
  compute((KT - 1) % 3);

  #pragma unroll
  for (int i = 0; i < 4; ++i)
    #pragma unroll
    for (int r = 0; r < 4; ++r) {
      const int mm = m0 + 64*wr + 16*i + 4*l4 + r;
      if (mm < nE) {
        const int id = pair[offE + mm];
        #pragma unroll
        for (int j = 0; j < 2; ++j)
          ybuf[(size_t)id * HD + n0 + 32*wc + 16*j + l15] = (_Float16)acc[i][j][r];
      }
    }
}

// ---------------- combine ----------------
__global__ void k_combine(const char* __restrict__ ws, float* __restrict__ out) {
  const int idx = blockIdx.x * blockDim.x + threadIdx.x;   // over T*HD/8
  const int t = idx >> 7, c = idx & 127;
  const float* topw = (const float*)(ws + WS_TOPW);
  const _Float16* yb = (const _Float16*)(ws + WS_YBUF);
  f16x8 y0 = ((const f16x8*)(yb + (size_t)(2*t)     * HD))[c];
  f16x8 y1 = ((const f16x8*)(yb + (size_t)(2*t + 1) * HD))[c];
  const float w0 = topw[2*t], w1 = topw[2*t+1];
  f32x4 o0, o1;
  #pragma unroll
  for (int j = 0; j < 4; ++j) {
    o0[j] = w0 * (float)y0[j]     + w1 * (float)y1[j];
    o1[j] = w0 * (float)y0[4 + j] + w1 * (float)y1[4 + j];
  }
  ((f32x4*)out)[2*idx]     = o0;
  ((f32x4*)out)[2*idx + 1] = o1;
}

extern "C" void kernel_launch(void* const* d_in, const int* in_sizes, int n_in,
                              void* d_out, int out_size, void* d_ws, size_t ws_size,
                              hipStream_t stream) {
  const float* hs     = (const float*)d_in[0];
  const float* logits = (const float*)d_in[1];
  const float* Wg     = (const float*)d_in[2];
  const float* Wu     = (const float*)d_in[3];
  const float* Wd     = (const float*)d_in[4];
  char* ws = (char*)d_ws;   // requires ~295 MB of workspace

  _Float16* hs16 = (_Float16*)(ws + WS_HS16);
  _Float16* wg16 = (_Float16*)(ws + WS_WG16);
  _Float16* wu16 = (_Float16*)(ws + WS_WU16);
  _Float16* wd16 = (_Float16*)(ws + WS_WD16);

  hipMemsetAsync(ws, 0, 256, stream);
  k_router <<<dim3(T_TOK/256), dim3(256), 0, stream>>>(logits, ws);
  k_prefix <<<dim3(1),         dim3(64),  0, stream>>>(ws);
  k_scatter<<<dim3(T_TOK/256), dim3(256), 0, stream>>>(ws);
  k_hscvt  <<<dim3(T_TOK*HD/4/256), dim3(256), 0, stream>>>(hs, hs16);
  k_wtrans <<<dim3(ID/64, HD/64, NE), dim3(256), 0, stream>>>(Wg, wg16, HD, ID);
  k_wtrans <<<dim3(ID/64, HD/64, NE), dim3(256), 0, stream>>>(Wu, wu16, HD, ID);
  k_wtrans <<<dim3(HD/64, ID/64, NE), dim3(256), 0, stream>>>(Wd, wd16, ID, HD);
  k_gemm1  <<<dim3(ID/BN, MAXTILES), dim3(512), 0, stream>>>(hs16, wg16, wu16, ws);
  k_gemm2  <<<dim3(HD/BN, MAXTILES), dim3(512), 0, stream>>>(wd16, ws);
  k_combine<<<dim3(T_TOK*HD/8/256), dim3(256), 0, stream>>>(ws, (float*)d_out);
}